// Round 6
// baseline (135.950 us; speedup 1.0000x reference)
//
#include <hip/hip_runtime.h>

#define B_DIM   2048
#define IN_DIM  4096
#define OUT_DIM 4096
#define FAN     64

// R11: kill the per-phase mask/weight reloads R10 exposed.
//  R10 post-mortem: addrs[64]+wv[64] = 128 regs > VGPR_Count 116 -> compiler
//  rolling-window reloads mask+weight from L2 EVERY phase (~37k cyc/CU,
//  matching the 40k gap between measured 123k cyc and the 83k LDS model).
//  Fix: split each output across a LANE PAIR (lane 2k: f 0..31, lane 2k+1:
//  f 32..63). Per-thread state halves to addrs[32]+wv[32]+8acc ~= 90 VGPR ->
//  naturally resident; asm-pinned so the compiler can't re-materialize via
//  reloads. Halves combine via DPP quad_perm(1,0,3,2) xor-1 add (VALU pipe,
//  NOT __shfl_xor which would lower to the saturated LDS pipe). Even lanes
//  store. Everything else = R10's proven shape: 8-row 16B cells,
//  ds_read_b128 gather, 128 KB double-buffer, 512 thr, launch_bounds(512,1)
//  (2nd arg = min WORKGROUPS/CU: (512,1) -> cap 256 VGPR, no spill).
//  Grid (16,16) = 256 blocks = 1/CU; 128 rows (16 tiles) per block.
//  LDS op count & conflict stats unchanged (4096 b128 wave-ops/CU, 64 random
//  cells per op) -> predict dur 51.4 -> ~36-41 us.

typedef float v2f __attribute__((ext_vector_type(2)));

__device__ __forceinline__ unsigned bf16_rne(float f) {
    unsigned u = __float_as_uint(f);
    return (u + 0x7fffu + ((u >> 16) & 1u)) >> 16;   // round-to-nearest-even bf16
}

// DPP xor-1 pairwise sum: quad_perm(1,0,3,2) = 0xB1. VALU pipe only.
__device__ __forceinline__ float xor1_sum(float x) {
    int p = __builtin_amdgcn_update_dpp(0, __float_as_int(x), 0xB1, 0xF, 0xF, true);
    return x + __int_as_float(p);
}

// ---------------- Phase 1: pack fp32 -> bf16 8-row cells ----------------
// Tile t = rows 8t..8t+7 (256 tiles); cell (t,c) = 16 B at wsp[t*4096 + c]:
// dw0 = bf16 rows(0,1), dw1 = rows(2,3), dw2 = rows(4,5), dw3 = rows(6,7).
__global__ __launch_bounds__(256) void pack_kernel(
    const float* __restrict__ input, uint4* __restrict__ wsp)
{
    const int idx = blockIdx.x * 256 + threadIdx.x;   // [0, 524288) cell-pairs
    const int t   = idx >> 11;                        // tile [0,256)
    const int c0  = (idx & 2047) << 1;                // column pair base

    const float* p = input + (size_t)t * 8 * IN_DIM + c0;
    float2 r[8];
    #pragma unroll
    for (int i = 0; i < 8; ++i)
        r[i] = *reinterpret_cast<const float2*>(p + i * IN_DIM);

    uint4 q0, q1;                                     // cells c0 and c0+1
    q0.x = bf16_rne(r[0].x) | (bf16_rne(r[1].x) << 16);
    q0.y = bf16_rne(r[2].x) | (bf16_rne(r[3].x) << 16);
    q0.z = bf16_rne(r[4].x) | (bf16_rne(r[5].x) << 16);
    q0.w = bf16_rne(r[6].x) | (bf16_rne(r[7].x) << 16);
    q1.x = bf16_rne(r[0].y) | (bf16_rne(r[1].y) << 16);
    q1.y = bf16_rne(r[2].y) | (bf16_rne(r[3].y) << 16);
    q1.z = bf16_rne(r[4].y) | (bf16_rne(r[5].y) << 16);
    q1.w = bf16_rne(r[6].y) | (bf16_rne(r[7].y) << 16);

    wsp[(size_t)t * 4096 + c0 + 0] = q0;
    wsp[(size_t)t * 4096 + c0 + 1] = q1;
}

// ---------------- Phase 2: pipelined gather + accumulate ----------------
__global__ __launch_bounds__(512, 1) void condensed_kernel(
    const uint4* __restrict__ wsp,
    const float* __restrict__ weight,
    const float* __restrict__ bias,
    const int*   __restrict__ mask,
    float*       __restrict__ out)
{
    __shared__ __align__(16) uint4 lds[8192];         // 128 KB = 2 x 64 KB buffers

    const int tid     = threadIdx.x;
    const int h       = tid & 1;                      // f-half: 0 -> [0,32), 1 -> [32,64)
    const int ol      = tid >> 1;                     // local output [0,256)
    const int o       = blockIdx.y * 256 + ol;
    const int tbase   = blockIdx.x * 16;              // 16 tiles of 8 rows
    const int rowbase = blockIdx.x * 128;             // 128 batch rows per block

    // ---- this thread's 32 LDS cell addresses + 32 weights, register-resident ----
    unsigned addrs[FAN / 2];
    float    wv[FAN / 2];
    {
        const int4*   mv = reinterpret_cast<const int4*>(mask   + o * FAN + h * 32);
        const float4* wp = reinterpret_cast<const float4*>(weight + o * FAN + h * 32);
        #pragma unroll
        for (int j = 0; j < 8; ++j) {
            int4   m4 = mv[j];
            float4 w4 = wp[j];
            addrs[4*j+0] = (unsigned)m4.x << 4;
            addrs[4*j+1] = (unsigned)m4.y << 4;
            addrs[4*j+2] = (unsigned)m4.z << 4;
            addrs[4*j+3] = (unsigned)m4.w << 4;
            wv[4*j+0] = w4.x;
            wv[4*j+1] = w4.y;
            wv[4*j+2] = w4.z;
            wv[4*j+3] = w4.w;
        }
    }
    // pin: forbid re-materialization (reload) of the arrays in later phases
    #pragma unroll
    for (int j = 0; j < FAN / 2; ++j) {
        asm volatile("" : "+v"(addrs[j]));
        asm volatile("" : "+v"(wv[j]));
    }
    const float bv = bias[o];

    // ---- prologue: DMA tile tbase -> buf0 (64 KB = 8 x 16 B per thread) ----
    {
        const uint4* src = wsp + (size_t)tbase * 4096 + tid;
        #pragma unroll
        for (int it = 0; it < 8; ++it) {
            __builtin_amdgcn_global_load_lds(
                (const __attribute__((address_space(1))) unsigned*)(src + it * 512),
                (__attribute__((address_space(3))) unsigned*)(lds + it * 512 + tid),
                16, 0, 0);
        }
    }
    __syncthreads();

    const char* ldsb = reinterpret_cast<const char*>(lds);

    for (int hp = 0; hp < 8; ++hp) {
        // ==== stage A: prefetch tile 2hp+1 -> buf1, compute tile 2hp (buf0) ====
        {
            const uint4* src = wsp + (size_t)(tbase + 2 * hp + 1) * 4096 + tid;
            #pragma unroll
            for (int it = 0; it < 8; ++it) {
                __builtin_amdgcn_global_load_lds(
                    (const __attribute__((address_space(1))) unsigned*)(src + it * 512),
                    (__attribute__((address_space(3))) unsigned*)(lds + 4096 + it * 512 + tid),
                    16, 0, 0);
            }
        }
        {
            v2f a01 = {0.f, 0.f}, a23 = {0.f, 0.f}, a45 = {0.f, 0.f}, a67 = {0.f, 0.f};
            #pragma unroll
            for (int j = 0; j < FAN / 2; ++j) {
                const uint4 g = *reinterpret_cast<const uint4*>(ldsb + addrs[j]);
                const v2f w2 = {wv[j], wv[j]};
                v2f v;
                v.x = __uint_as_float(g.x << 16);
                v.y = __uint_as_float(g.x & 0xffff0000u);
                a01 = __builtin_elementwise_fma(v, w2, a01);
                v.x = __uint_as_float(g.y << 16);
                v.y = __uint_as_float(g.y & 0xffff0000u);
                a23 = __builtin_elementwise_fma(v, w2, a23);
                v.x = __uint_as_float(g.z << 16);
                v.y = __uint_as_float(g.z & 0xffff0000u);
                a45 = __builtin_elementwise_fma(v, w2, a45);
                v.x = __uint_as_float(g.w << 16);
                v.y = __uint_as_float(g.w & 0xffff0000u);
                a67 = __builtin_elementwise_fma(v, w2, a67);
            }
            const float s0 = xor1_sum(a01.x), s1 = xor1_sum(a01.y);
            const float s2 = xor1_sum(a23.x), s3 = xor1_sum(a23.y);
            const float s4 = xor1_sum(a45.x), s5 = xor1_sum(a45.y);
            const float s6 = xor1_sum(a67.x), s7 = xor1_sum(a67.y);
            if (h == 0) {
                float* op = out + (size_t)(rowbase + 8 * (2 * hp)) * OUT_DIM + o;
                op[0 * OUT_DIM] = s0 + bv;
                op[1 * OUT_DIM] = s1 + bv;
                op[2 * OUT_DIM] = s2 + bv;
                op[3 * OUT_DIM] = s3 + bv;
                op[4 * OUT_DIM] = s4 + bv;
                op[5 * OUT_DIM] = s5 + bv;
                op[6 * OUT_DIM] = s6 + bv;
                op[7 * OUT_DIM] = s7 + bv;
            }
        }
        __syncthreads();   // buf0 free; DMA(-> buf1) drained

        // ==== stage B: prefetch tile 2hp+2 -> buf0, compute tile 2hp+1 (buf1) ====
        if (hp < 7) {
            const uint4* src = wsp + (size_t)(tbase + 2 * hp + 2) * 4096 + tid;
            #pragma unroll
            for (int it = 0; it < 8; ++it) {
                __builtin_amdgcn_global_load_lds(
                    (const __attribute__((address_space(1))) unsigned*)(src + it * 512),
                    (__attribute__((address_space(3))) unsigned*)(lds + it * 512 + tid),
                    16, 0, 0);
            }
        }
        {
            v2f a01 = {0.f, 0.f}, a23 = {0.f, 0.f}, a45 = {0.f, 0.f}, a67 = {0.f, 0.f};
            #pragma unroll
            for (int j = 0; j < FAN / 2; ++j) {
                // +65536 = buf1 (doesn't fit ds offset field; costs one v_add/op)
                const uint4 g = *reinterpret_cast<const uint4*>(ldsb + 65536 + addrs[j]);
                const v2f w2 = {wv[j], wv[j]};
                v2f v;
                v.x = __uint_as_float(g.x << 16);
                v.y = __uint_as_float(g.x & 0xffff0000u);
                a01 = __builtin_elementwise_fma(v, w2, a01);
                v.x = __uint_as_float(g.y << 16);
                v.y = __uint_as_float(g.y & 0xffff0000u);
                a23 = __builtin_elementwise_fma(v, w2, a23);
                v.x = __uint_as_float(g.z << 16);
                v.y = __uint_as_float(g.z & 0xffff0000u);
                a45 = __builtin_elementwise_fma(v, w2, a45);
                v.x = __uint_as_float(g.w << 16);
                v.y = __uint_as_float(g.w & 0xffff0000u);
                a67 = __builtin_elementwise_fma(v, w2, a67);
            }
            const float s0 = xor1_sum(a01.x), s1 = xor1_sum(a01.y);
            const float s2 = xor1_sum(a23.x), s3 = xor1_sum(a23.y);
            const float s4 = xor1_sum(a45.x), s5 = xor1_sum(a45.y);
            const float s6 = xor1_sum(a67.x), s7 = xor1_sum(a67.y);
            if (h == 0) {
                float* op = out + (size_t)(rowbase + 8 * (2 * hp + 1)) * OUT_DIM + o;
                op[0 * OUT_DIM] = s0 + bv;
                op[1 * OUT_DIM] = s1 + bv;
                op[2 * OUT_DIM] = s2 + bv;
                op[3 * OUT_DIM] = s3 + bv;
                op[4 * OUT_DIM] = s4 + bv;
                op[5 * OUT_DIM] = s5 + bv;
                op[6 * OUT_DIM] = s6 + bv;
                op[7 * OUT_DIM] = s7 + bv;
            }
        }
        __syncthreads();   // buf1 free; DMA(-> buf0) drained
    }
}

extern "C" void kernel_launch(void* const* d_in, const int* in_sizes, int n_in,
                              void* d_out, int out_size, void* d_ws, size_t ws_size,
                              hipStream_t stream) {
    const float* input  = (const float*)d_in[0];
    const float* weight = (const float*)d_in[1];
    const float* bias   = (const float*)d_in[2];
    const int*   mask   = (const int*)d_in[3];
    float*       out    = (float*)d_out;
    uint4*       wsp    = (uint4*)d_ws;               // needs 16 MiB

    pack_kernel<<<2048, 256, 0, stream>>>(input, wsp);
    dim3 grid(16, 16);  // 256 blocks = exactly 1/CU (128 KB LDS, 512 threads)
    condensed_kernel<<<grid, 512, 0, stream>>>(wsp, weight, bias, mask, out);
}